// Round 1
// baseline (745.400 us; speedup 1.0000x reference)
//
#include <hip/hip_runtime.h>
#include <hip/hip_cooperative_groups.h>
#include <stddef.h>

namespace cg = cooperative_groups;

#define B_ 4
#define N_ 2048
#define C_ 512
#define H_ 8
#define D_ 64
#define M_ 4
#define HM_ 32
#define S_ 64            // n-chunks for flash split (n-chunk = 32)
#define SCALE_ 0.125f

// workspace layout in floats (identical to verified 5-kernel version)
#define QK_OFF   0                        // 4*32*512      = 65536
#define PAX_OFF  65536                    // 64*4*32*512   = 4194304
#define MLOC_OFF (65536 + 4194304)        // 8192
#define LLOC_OFF (MLOC_OFF + 8192)        // 8192
#define QP_OFF   (LLOC_OFF + 8192)        // 8*16*512      = 65536
#define OVP_OFF  (QP_OFF + 65536)         // 8*16*512      = 65536
// total ~17.6 MB

struct SmemGemm {            // phases 1 (q), 2 (qk), 5 (out) — 21.8 KB
    float W[64][68];
    float xr[16][68];
};
struct SmemFlash {           // phase 3 — 92.8 KB (the max; 1 block/CU)
    float qk_s[32][516];     // pitch 516 -> conflict-free b128
    float scratch[4][32][32];
    float dmat[32][36];
    float pT[32][36];
    float mrow[32];
    float red8[32][8];
};
struct SmemOV {              // phase 4 — 27.0 KB
    float Wv[64][68];
    float axh[16][68];
    float sc[64][16];
    float redm[16][16];
    float mgl[16];
    float lgl[16];
};
union __align__(16) SmemAll {
    SmemGemm g;
    SmemFlash f;
    SmemOV o;
};

// ONE cooperative kernel: 256 blocks x 256 threads, 1 block/CU (LDS 92.8KB).
// Phase boundaries are grid.sync() instead of kernel relaunches.
__global__ __launch_bounds__(256) void fused_attn(
        const float* __restrict__ x, const float* __restrict__ bias,
        const float* __restrict__ Wq, const float* __restrict__ Wkv,
        const float* __restrict__ Wo, const float* __restrict__ bo,
        float* __restrict__ out, float* __restrict__ ws) {
    cg::grid_group gridg = cg::this_grid();
    __shared__ SmemAll sm;

    float* qk_ws   = ws + QK_OFF;
    float* pax     = ws + PAX_OFF;
    float* mloc    = ws + MLOC_OFF;
    float* lloc    = ws + LLOC_OFF;
    float* q_part  = ws + QP_OFF;
    float* ov_part = ws + OVP_OFF;

    const int t = threadIdx.x;
    const int bid = blockIdx.x;

    // ============ phase 1: q_part (blocks 0-63) + zero out (blocks 64-95) ====
    if (bid < 64) {
        int c0 = (bid & 7) * 64, j0 = (bid >> 3) * 64;
        #pragma unroll
        for (int i = 0; i < 4; i++) {
            int f = t + i * 256; int cc = f >> 4, j4 = f & 15;
            *(float4*)&sm.g.W[cc][j4 * 4] = *(const float4*)&Wq[(size_t)(c0 + cc) * 512 + j0 + j4 * 4];
        }
        {
            int r = t >> 4, c4 = t & 15;
            int b = r >> 2, m = r & 3;
            *(float4*)&sm.g.xr[r][c4 * 4] = *(const float4*)&x[((size_t)(b * N_) + m) * C_ + c0 + c4 * 4];
        }
        __syncthreads();
        int j = t & 63, rg = t >> 6;
        float acc[4] = {0, 0, 0, 0};
        #pragma unroll 16
        for (int cc = 0; cc < 64; cc++) {
            float w = sm.g.W[cc][j];
            #pragma unroll
            for (int i = 0; i < 4; i++) acc[i] += sm.g.xr[rg * 4 + i][cc] * w;
        }
        #pragma unroll
        for (int i = 0; i < 4; i++) {
            int r = rg * 4 + i;
            q_part[((size_t)(bid & 7) * 16 + r) * 512 + j0 + j] = acc[i];
        }
    } else if (bid < 96) {
        out[(bid - 64) * 256 + t] = 0.f;   // 32*256 = 8192 = full out (for phase-5 atomics)
    }
    gridg.sync();

    // ============ phase 2: qk = q @ Wk^T * SCALE (blocks 0-63) ===============
    if (bid < 64) {
        int c0 = (bid & 7) * 64; int h = bid >> 3;
        #pragma unroll
        for (int i = 0; i < 4; i++) {
            int f = t + i * 256; int cc = f >> 4, d4 = f & 15;
            float4 v = *(const float4*)&Wkv[(size_t)(c0 + cc) * 1024 + h * 64 + d4 * 4];
            sm.g.W[d4 * 4 + 0][cc] = v.x; sm.g.W[d4 * 4 + 1][cc] = v.y;  // W reused as WkT[d][cc]
            sm.g.W[d4 * 4 + 2][cc] = v.z; sm.g.W[d4 * 4 + 3][cc] = v.w;
        }
        {
            int r = t >> 4, d4 = t & 15;
            float4 a = make_float4(0.f, 0.f, 0.f, 0.f);
            #pragma unroll
            for (int cs = 0; cs < 8; cs++) {
                float4 v = *(const float4*)&q_part[((size_t)cs * 16 + r) * 512 + h * 64 + d4 * 4];
                a.x += v.x; a.y += v.y; a.z += v.z; a.w += v.w;
            }
            *(float4*)&sm.g.xr[r][d4 * 4] = a;                            // xr reused as qh[r][d]
        }
        __syncthreads();
        int c = t & 63, rg = t >> 6;
        float acc[4] = {0, 0, 0, 0};
        #pragma unroll 16
        for (int d = 0; d < 64; d++) {
            float w = sm.g.W[d][c];
            #pragma unroll
            for (int i = 0; i < 4; i++) acc[i] += sm.g.xr[rg * 4 + i][d] * w;
        }
        #pragma unroll
        for (int i = 0; i < 4; i++) {
            int r = rg * 4 + i; int b = r >> 2, m = r & 3;
            qk_ws[((size_t)(b * HM_) + h * M_ + m) * 512 + c0 + c] = acc[i] * SCALE_;
        }
    }
    gridg.sync();

    // ============ phase 3: flash chunk (all 256 blocks) ======================
    {
        int s = bid & 63, b = bid >> 6;
        int n0 = s * 32;

        // stage qk rows for this b (32 x 512)
        #pragma unroll
        for (int k = 0; k < 16; k++) {
            int idx = t + k * 256;           // 0..4095 float4s
            int row = idx >> 7, c4 = idx & 127;
            *(float4*)&sm.f.qk_s[row][c4 * 4] =
                *(const float4*)&qk_ws[((size_t)(b * HM_) + row) * 512 + c4 * 4];
        }
        __syncthreads();

        // ---- dots: thread tile 8hm x 4n, 8-way c-split ----
        int hmg = t >> 6;            // 0..3 (= wave)
        int ng  = (t >> 3) & 7;      // 0..7
        int cs  = t & 7;             // 0..7
        float d[8][4];
        #pragma unroll
        for (int i = 0; i < 8; i++)
            #pragma unroll
            for (int jn = 0; jn < 4; jn++) d[i][jn] = 0.f;

        const float* xp = &x[((size_t)(b * N_) + n0 + ng * 4) * C_];
        const float* qrow = &sm.f.qk_s[hmg * 8][0];
        #pragma unroll 2
        for (int step = 0; step < 16; step++) {
            int cbase = cs * 4 + step * 32;
            float4 xv[4];
            #pragma unroll
            for (int jn = 0; jn < 4; jn++)
                xv[jn] = *(const float4*)&xp[(size_t)jn * C_ + cbase];
            #pragma unroll
            for (int i = 0; i < 8; i++) {
                float4 qv = *(const float4*)&qrow[i * 516 + cbase];
                #pragma unroll
                for (int jn = 0; jn < 4; jn++) {
                    d[i][jn] += qv.x * xv[jn].x + qv.y * xv[jn].y + qv.z * xv[jn].z + qv.w * xv[jn].w;
                }
            }
        }
        // split-reduce over cs (8 -> 1), 3 rounds
        int pos = hmg * 8 + ng;
        if (cs >= 4) {
            #pragma unroll
            for (int i = 0; i < 8; i++)
                *(float4*)&sm.f.scratch[cs - 4][pos][i * 4] = make_float4(d[i][0], d[i][1], d[i][2], d[i][3]);
        }
        __syncthreads();
        if (cs < 4) {
            #pragma unroll
            for (int i = 0; i < 8; i++) {
                float4 v = *(float4*)&sm.f.scratch[cs][pos][i * 4];
                d[i][0] += v.x; d[i][1] += v.y; d[i][2] += v.z; d[i][3] += v.w;
            }
        }
        __syncthreads();
        if (cs == 2 || cs == 3) {
            #pragma unroll
            for (int i = 0; i < 8; i++)
                *(float4*)&sm.f.scratch[cs - 2][pos][i * 4] = make_float4(d[i][0], d[i][1], d[i][2], d[i][3]);
        }
        __syncthreads();
        if (cs < 2) {
            #pragma unroll
            for (int i = 0; i < 8; i++) {
                float4 v = *(float4*)&sm.f.scratch[cs][pos][i * 4];
                d[i][0] += v.x; d[i][1] += v.y; d[i][2] += v.z; d[i][3] += v.w;
            }
        }
        __syncthreads();
        if (cs == 1) {
            #pragma unroll
            for (int i = 0; i < 8; i++)
                *(float4*)&sm.f.scratch[0][pos][i * 4] = make_float4(d[i][0], d[i][1], d[i][2], d[i][3]);
        }
        __syncthreads();
        if (cs == 0) {
            #pragma unroll
            for (int i = 0; i < 8; i++) {
                float4 v = *(float4*)&sm.f.scratch[0][pos][i * 4];
                *(float4*)&sm.f.dmat[hmg * 8 + i][ng * 4] =
                    make_float4(d[i][0] + v.x, d[i][1] + v.y, d[i][2] + v.z, d[i][3] + v.w);
            }
        }
        __syncthreads();

        // ---- bias + local softmax ----
        int row = t >> 3, j = t & 7;   // row = hm, 8 threads/row over 32 n
        int h = row >> 2, m = row & 3;
        float4 dv = *(float4*)&sm.f.dmat[row][j * 4];
        float4 bv = *(const float4*)&bias[(((size_t)(b * H_) + h) * N_ + m) * N_ + n0 + j * 4];
        float v0 = dv.x + bv.x, v1 = dv.y + bv.y, v2 = dv.z + bv.z, v3 = dv.w + bv.w;
        float pmax = fmaxf(fmaxf(v0, v1), fmaxf(v2, v3));
        sm.f.red8[row][j] = pmax;
        __syncthreads();
        if (j == 0) {
            float mg = sm.f.red8[row][0];
            #pragma unroll
            for (int k = 1; k < 8; k++) mg = fmaxf(mg, sm.f.red8[row][k]);
            sm.f.mrow[row] = mg;
        }
        __syncthreads();
        float mg = sm.f.mrow[row];
        float e0 = __expf(v0 - mg), e1 = __expf(v1 - mg), e2 = __expf(v2 - mg), e3 = __expf(v3 - mg);
        sm.f.red8[row][j] = e0 + e1 + e2 + e3;
        __syncthreads();
        if (j == 0) {
            float ls = sm.f.red8[row][0];
            #pragma unroll
            for (int k = 1; k < 8; k++) ls += sm.f.red8[row][k];
            mloc[((size_t)(s * B_) + b) * HM_ + row] = mg;
            lloc[((size_t)(s * B_) + b) * HM_ + row] = ls;
        }
        sm.f.pT[j * 4 + 0][row] = e0; sm.f.pT[j * 4 + 1][row] = e1;
        sm.f.pT[j * 4 + 2][row] = e2; sm.f.pT[j * 4 + 3][row] = e3;
        __syncthreads();

        // ---- pax = p^T-weighted x. thread tile 8hm x 8c ----
        int cg = t & 63, hw = t >> 6;  // hw = wave = hm-group
        float o[8][8];
        #pragma unroll
        for (int i = 0; i < 8; i++)
            #pragma unroll
            for (int jj = 0; jj < 8; jj++) o[i][jj] = 0.f;
        const float* xb = &x[((size_t)(b * N_) + n0) * C_];
        #pragma unroll 4
        for (int n = 0; n < 32; n++) {
            float4 pa = *(float4*)&sm.f.pT[n][hw * 8];
            float4 pb = *(float4*)&sm.f.pT[n][hw * 8 + 4];
            float4 xa = *(const float4*)&xb[(size_t)n * C_ + cg * 4];
            float4 xc = *(const float4*)&xb[(size_t)n * C_ + 256 + cg * 4];
            float pv[8] = {pa.x, pa.y, pa.z, pa.w, pb.x, pb.y, pb.z, pb.w};
            #pragma unroll
            for (int i = 0; i < 8; i++) {
                o[i][0] += pv[i] * xa.x; o[i][1] += pv[i] * xa.y;
                o[i][2] += pv[i] * xa.z; o[i][3] += pv[i] * xa.w;
                o[i][4] += pv[i] * xc.x; o[i][5] += pv[i] * xc.y;
                o[i][6] += pv[i] * xc.z; o[i][7] += pv[i] * xc.w;
            }
        }
        #pragma unroll
        for (int i = 0; i < 8; i++) {
            int hm = hw * 8 + i;
            float* dst = &pax[(((size_t)(s * B_) + b) * HM_ + hm) * 512];
            *(float4*)&dst[cg * 4]       = make_float4(o[i][0], o[i][1], o[i][2], o[i][3]);
            *(float4*)&dst[256 + cg * 4] = make_float4(o[i][4], o[i][5], o[i][6], o[i][7]);
        }
    }
    gridg.sync();

    // ============ phase 4: combine flash partials + Wv (blocks 0-63) =========
    if (bid < 64) {
        int c0 = (bid & 7) * 64; int h = bid >> 3;
        #pragma unroll
        for (int i = 0; i < 4; i++) {
            int f = t + i * 256; int cc = f >> 4, e4 = f & 15;
            *(float4*)&sm.o.Wv[cc][e4 * 4] =
                *(const float4*)&Wkv[(size_t)(c0 + cc) * 1024 + 512 + h * 64 + e4 * 4];
        }
        // scale factors
        int r = t & 15, sg = t >> 4;   // 16 s-groups x 4 s
        int b = r >> 2, m = r & 3;
        float pm = -1e30f;
        #pragma unroll
        for (int k = 0; k < 4; k++) {
            int s = sg * 4 + k;
            pm = fmaxf(pm, mloc[((size_t)(s * B_) + b) * HM_ + h * M_ + m]);
        }
        sm.o.redm[sg][r] = pm;
        __syncthreads();
        if (t < 16) {
            float mgv = sm.o.redm[0][t];
            #pragma unroll
            for (int k = 1; k < 16; k++) mgv = fmaxf(mgv, sm.o.redm[k][t]);
            sm.o.mgl[t] = mgv;
        }
        __syncthreads();
        float mgv = sm.o.mgl[r];
        float pl = 0.f;
        #pragma unroll
        for (int k = 0; k < 4; k++) {
            int s = sg * 4 + k;
            float w = __expf(mloc[((size_t)(s * B_) + b) * HM_ + h * M_ + m] - mgv);
            sm.o.sc[s][r] = w;
            pl += w * lloc[((size_t)(s * B_) + b) * HM_ + h * M_ + m];
        }
        sm.o.redm[sg][r] = pl;
        __syncthreads();
        if (t < 16) {
            float l = sm.o.redm[0][t];
            #pragma unroll
            for (int k = 1; k < 16; k++) l += sm.o.redm[k][t];
            sm.o.lgl[t] = 1.0f / l;
        }
        __syncthreads();
        float inv = sm.o.lgl[r];
        #pragma unroll
        for (int k = 0; k < 4; k++) sm.o.sc[sg * 4 + k][r] *= inv;
        __syncthreads();
        // axh = sum_s scale * pax  (unroll 8 -> 8 outstanding global loads)
        {
            int rr = t >> 4, c4 = t & 15;
            int bb = rr >> 2, mm = rr & 3;
            float4 a = make_float4(0.f, 0.f, 0.f, 0.f);
            #pragma unroll 8
            for (int s = 0; s < 64; s++) {
                float w = sm.o.sc[s][rr];
                float4 v = *(const float4*)&pax[(((size_t)(s * B_) + bb) * HM_ + h * M_ + mm) * 512 + c0 + c4 * 4];
                a.x += w * v.x; a.y += w * v.y; a.z += w * v.z; a.w += w * v.w;
            }
            *(float4*)&sm.o.axh[rr][c4 * 4] = a;
        }
        __syncthreads();
        int e = t & 63, rg = t >> 6;
        float acc[4] = {0, 0, 0, 0};
        #pragma unroll 16
        for (int cc = 0; cc < 64; cc++) {
            float w = sm.o.Wv[cc][e];
            #pragma unroll
            for (int i = 0; i < 4; i++) acc[i] += sm.o.axh[rg * 4 + i][cc] * w;
        }
        #pragma unroll
        for (int i = 0; i < 4; i++) {
            int rr = rg * 4 + i;
            ov_part[((size_t)(bid & 7) * 16 + rr) * 512 + h * 64 + e] = acc[i];
        }
    }
    gridg.sync();

    // ============ phase 5: out = ov @ Wo + bo (blocks 0-63, atomic i-split) ==
    if (bid < 64) {
        int i0 = (bid & 7) * 64; int j0 = (bid >> 3) * 64;
        #pragma unroll
        for (int i = 0; i < 4; i++) {
            int f = t + i * 256; int ii = f >> 4, j4 = f & 15;
            *(float4*)&sm.g.W[ii][j4 * 4] = *(const float4*)&Wo[(size_t)(i0 + ii) * 512 + j0 + j4 * 4];
        }
        {
            int r = t >> 4, c4 = t & 15;
            float4 a = make_float4(0.f, 0.f, 0.f, 0.f);
            #pragma unroll
            for (int cs = 0; cs < 8; cs++) {
                float4 v = *(const float4*)&ov_part[((size_t)cs * 16 + r) * 512 + i0 + c4 * 4];
                a.x += v.x; a.y += v.y; a.z += v.z; a.w += v.w;
            }
            *(float4*)&sm.g.xr[r][c4 * 4] = a;
        }
        __syncthreads();
        int j = t & 63, rg = t >> 6;
        float binit = ((bid & 7) == 0) ? bo[j0 + j] : 0.f;
        float acc[4] = {binit, binit, binit, binit};
        #pragma unroll 16
        for (int ii = 0; ii < 64; ii++) {
            float w = sm.g.W[ii][j];
            #pragma unroll
            for (int i = 0; i < 4; i++) acc[i] += sm.g.xr[rg * 4 + i][ii] * w;
        }
        #pragma unroll
        for (int i = 0; i < 4; i++) {
            int r = rg * 4 + i;
            atomicAdd(&out[r * 512 + j0 + j], acc[i]);
        }
    }
}

extern "C" void kernel_launch(void* const* d_in, const int* in_sizes, int n_in,
                              void* d_out, int out_size, void* d_ws, size_t ws_size,
                              hipStream_t stream) {
    (void)in_sizes; (void)n_in; (void)out_size; (void)ws_size;
    const float* x    = (const float*)d_in[0];
    const float* bias = (const float*)d_in[1];
    const float* Wq   = (const float*)d_in[2];
    const float* Wkv  = (const float*)d_in[3];
    const float* Wo   = (const float*)d_in[4];
    const float* bo   = (const float*)d_in[5];
    float* out = (float*)d_out;
    float* ws  = (float*)d_ws;

    void* args[8] = {&x, &bias, &Wq, &Wkv, &Wo, &bo, &out, &ws};
    hipLaunchCooperativeKernel((void*)fused_attn, dim3(256), dim3(256), args, 0, stream);
}

// Round 2
// 627.617 us; speedup vs baseline: 1.1877x; 1.1877x over previous
//
#include <hip/hip_runtime.h>
#include <stddef.h>

#define B_ 4
#define N_ 2048
#define C_ 512
#define H_ 8
#define D_ 64
#define M_ 4
#define HM_ 32
#define S_ 64            // n-chunks for flash split (n-chunk = 32)
#define SCALE_ 0.125f

// workspace layout in floats
#define QK_OFF   0                        // 4*32*512      = 65536
#define PAX_OFF  65536                    // 64*4*32*512   = 4194304
#define MLOC_OFF (65536 + 4194304)        // 8192
#define LLOC_OFF (MLOC_OFF + 8192)        // 8192
#define OVP_OFF  (LLOC_OFF + 8192)        // 32*16*512     = 262144
// total ~18 MB

// Merged q+qk: block (c0-slice, h). Computes qh = x_q @ Wq[:, h*64..] fully
// (8-chunk K loop), then qk slice = qh @ Wk[c0:c0+64, h]^T * SCALE.
// Also zeroes `out` (needed by k5b atomics).
__global__ __launch_bounds__(256) void k1_qk(const float* __restrict__ x, const float* __restrict__ Wq,
                                             const float* __restrict__ Wkv,
                                             float* __restrict__ qk_ws, float* __restrict__ out) {
    __shared__ float W[64][68];
    __shared__ float xr[16][68];
    __shared__ float qh[16][68];
    int t = threadIdx.x;
    int c0 = blockIdx.x * 64; int h = blockIdx.y;
    int bid = blockIdx.y * 8 + blockIdx.x;
    if (bid < 32) out[bid * 256 + t] = 0.f;   // 32*256 = 8192 = out size

    int j = t & 63, rg = t >> 6;
    float qacc[4] = {0, 0, 0, 0};
    // q GEMM over K=512 in 8 chunks of 64
    for (int ch = 0; ch < 8; ch++) {
        int cc0 = ch * 64;
        #pragma unroll
        for (int i = 0; i < 4; i++) {
            int f = t + i * 256; int cc = f >> 4, j4 = f & 15;
            *(float4*)&W[cc][j4 * 4] = *(const float4*)&Wq[(size_t)(cc0 + cc) * 512 + h * 64 + j4 * 4];
        }
        {
            int r = t >> 4, c4 = t & 15;
            int b = r >> 2, m = r & 3;
            *(float4*)&xr[r][c4 * 4] = *(const float4*)&x[((size_t)(b * N_) + m) * C_ + cc0 + c4 * 4];
        }
        __syncthreads();
        #pragma unroll 16
        for (int cc = 0; cc < 64; cc++) {
            float w = W[cc][j];
            #pragma unroll
            for (int i = 0; i < 4; i++) qacc[i] += xr[rg * 4 + i][cc] * w;
        }
        __syncthreads();
    }
    // qh -> LDS; stage WkT[d][cc] (transposed) for this c0
    #pragma unroll
    for (int i = 0; i < 4; i++) qh[rg * 4 + i][j] = qacc[i];
    #pragma unroll
    for (int i = 0; i < 4; i++) {
        int f = t + i * 256; int cc = f >> 4, d4 = f & 15;
        float4 v = *(const float4*)&Wkv[(size_t)(c0 + cc) * 1024 + h * 64 + d4 * 4];
        W[d4 * 4 + 0][cc] = v.x; W[d4 * 4 + 1][cc] = v.y;
        W[d4 * 4 + 2][cc] = v.z; W[d4 * 4 + 3][cc] = v.w;
    }
    __syncthreads();
    int c = j;
    float acc[4] = {0, 0, 0, 0};
    #pragma unroll 16
    for (int d = 0; d < 64; d++) {
        float w = W[d][c];
        #pragma unroll
        for (int i = 0; i < 4; i++) acc[i] += qh[rg * 4 + i][d] * w;
    }
    #pragma unroll
    for (int i = 0; i < 4; i++) {
        int r = rg * 4 + i; int b = r >> 2, m = r & 3;
        qk_ws[((size_t)(b * HM_) + h * M_ + m) * 512 + c0 + c] = acc[i] * SCALE_;
    }
}

// Fused flash chunk: per (s, b): dots(32hm x 32n over K=512) + bias -> local softmax (m,l)
// -> pax[s][b][hm][c] = sum_n exp(dots - m_loc) * x[n][c]   (unnormalized)
// cs-split reduce is now an in-wave shfl_xor butterfly (cs = lane&7).
__global__ __launch_bounds__(256) void k234_flash(const float* __restrict__ x, const float* __restrict__ qk_ws,
                                                  const float* __restrict__ bias,
                                                  float* __restrict__ pax, float* __restrict__ mloc,
                                                  float* __restrict__ lloc) {
    __shared__ __align__(16) float qk_s[32][516];      // 66 KB, pitch 516 -> conflict-free b128
    __shared__ __align__(16) float dmat[32][36];
    __shared__ __align__(16) float pT[32][36];         // p transposed [n][hm]
    __shared__ float mrow[32];
    __shared__ float red8[32][8];
    int t = threadIdx.x;
    int s = blockIdx.x, b = blockIdx.y;
    int n0 = s * 32;

    // stage qk rows for this b (32 x 512)
    #pragma unroll
    for (int k = 0; k < 16; k++) {
        int idx = t + k * 256;           // 0..4095 float4s
        int row = idx >> 7, c4 = idx & 127;
        *(float4*)&qk_s[row][c4 * 4] =
            *(const float4*)&qk_ws[((size_t)(b * HM_) + row) * 512 + c4 * 4];
    }
    __syncthreads();

    // ---- phase 1: dots. thread tile 8hm x 4n, 8-way c-split ----
    int hmg = t >> 6;            // 0..3 (= wave)
    int ng  = (t >> 3) & 7;      // 0..7
    int cs  = t & 7;             // 0..7
    float d[8][4];
    #pragma unroll
    for (int i = 0; i < 8; i++)
        #pragma unroll
        for (int jn = 0; jn < 4; jn++) d[i][jn] = 0.f;

    const float* xp = &x[((size_t)(b * N_) + n0 + ng * 4) * C_];
    const float* qrow = &qk_s[hmg * 8][0];
    #pragma unroll 2
    for (int step = 0; step < 16; step++) {
        int cbase = cs * 4 + step * 32;
        float4 xv[4];
        #pragma unroll
        for (int jn = 0; jn < 4; jn++)
            xv[jn] = *(const float4*)&xp[(size_t)jn * C_ + cbase];
        #pragma unroll
        for (int i = 0; i < 8; i++) {
            float4 qv = *(const float4*)&qrow[i * 516 + cbase];
            #pragma unroll
            for (int jn = 0; jn < 4; jn++) {
                d[i][jn] += qv.x * xv[jn].x + qv.y * xv[jn].y + qv.z * xv[jn].z + qv.w * xv[jn].w;
            }
        }
    }
    // in-wave butterfly reduce over cs (lane = ng*8+cs; xor 1/2/4 flips cs only)
    #pragma unroll
    for (int i = 0; i < 8; i++) {
        #pragma unroll
        for (int jn = 0; jn < 4; jn++) {
            d[i][jn] += __shfl_xor(d[i][jn], 1, 64);
            d[i][jn] += __shfl_xor(d[i][jn], 2, 64);
            d[i][jn] += __shfl_xor(d[i][jn], 4, 64);
        }
    }
    if (cs == 0) {
        #pragma unroll
        for (int i = 0; i < 8; i++)
            *(float4*)&dmat[hmg * 8 + i][ng * 4] = make_float4(d[i][0], d[i][1], d[i][2], d[i][3]);
    }
    __syncthreads();

    // ---- phase 2: bias + local softmax ----
    int row = t >> 3, j = t & 7;   // row = hm, 8 threads/row over 32 n
    int h = row >> 2, m = row & 3;
    float4 dv = *(float4*)&dmat[row][j * 4];
    float4 bv = *(const float4*)&bias[(((size_t)(b * H_) + h) * N_ + m) * N_ + n0 + j * 4];
    float v0 = dv.x + bv.x, v1 = dv.y + bv.y, v2 = dv.z + bv.z, v3 = dv.w + bv.w;
    float pmax = fmaxf(fmaxf(v0, v1), fmaxf(v2, v3));
    red8[row][j] = pmax;
    __syncthreads();
    if (j == 0) {
        float mg = red8[row][0];
        #pragma unroll
        for (int k = 1; k < 8; k++) mg = fmaxf(mg, red8[row][k]);
        mrow[row] = mg;
    }
    __syncthreads();
    float mg = mrow[row];
    float e0 = __expf(v0 - mg), e1 = __expf(v1 - mg), e2 = __expf(v2 - mg), e3 = __expf(v3 - mg);
    red8[row][j] = e0 + e1 + e2 + e3;
    __syncthreads();
    if (j == 0) {
        float ls = red8[row][0];
        #pragma unroll
        for (int k = 1; k < 8; k++) ls += red8[row][k];
        mloc[((size_t)(s * B_) + b) * HM_ + row] = mg;
        lloc[((size_t)(s * B_) + b) * HM_ + row] = ls;
    }
    pT[j * 4 + 0][row] = e0; pT[j * 4 + 1][row] = e1;
    pT[j * 4 + 2][row] = e2; pT[j * 4 + 3][row] = e3;
    __syncthreads();

    // ---- phase 3: pax = p^T-weighted x. thread tile 8hm x 8c ----
    int cg = t & 63, hw = t >> 6;  // hw = wave = hm-group
    float o[8][8];
    #pragma unroll
    for (int i = 0; i < 8; i++)
        #pragma unroll
        for (int jj = 0; jj < 8; jj++) o[i][jj] = 0.f;
    const float* xb = &x[((size_t)(b * N_) + n0) * C_];
    #pragma unroll 4
    for (int n = 0; n < 32; n++) {
        float4 pa = *(float4*)&pT[n][hw * 8];
        float4 pb = *(float4*)&pT[n][hw * 8 + 4];
        float4 xa = *(const float4*)&xb[(size_t)n * C_ + cg * 4];
        float4 xc = *(const float4*)&xb[(size_t)n * C_ + 256 + cg * 4];
        float pv[8] = {pa.x, pa.y, pa.z, pa.w, pb.x, pb.y, pb.z, pb.w};
        #pragma unroll
        for (int i = 0; i < 8; i++) {
            o[i][0] += pv[i] * xa.x; o[i][1] += pv[i] * xa.y;
            o[i][2] += pv[i] * xa.z; o[i][3] += pv[i] * xa.w;
            o[i][4] += pv[i] * xc.x; o[i][5] += pv[i] * xc.y;
            o[i][6] += pv[i] * xc.z; o[i][7] += pv[i] * xc.w;
        }
    }
    #pragma unroll
    for (int i = 0; i < 8; i++) {
        int hm = hw * 8 + i;
        float* dst = &pax[(((size_t)(s * B_) + b) * HM_ + hm) * 512];
        *(float4*)&dst[cg * 4]       = make_float4(o[i][0], o[i][1], o[i][2], o[i][3]);
        *(float4*)&dst[256 + cg * 4] = make_float4(o[i][4], o[i][5], o[i][6], o[i][7]);
    }
}

// combine flash partials (scale by exp(m_loc - m_g)/l_g) then project with Wv.
// 4-way s-split over gridDim.z: slice = z*8 + c0-slice. ov_part[slice][r][h*64+e]
__global__ __launch_bounds__(256) void k5a_ov(const float* __restrict__ Wkv, const float* __restrict__ pax,
                                              const float* __restrict__ mloc, const float* __restrict__ lloc,
                                              float* __restrict__ ov_part) {
    __shared__ float Wv[64][68];   // [cc][e]
    __shared__ float axh[16][68];  // [r][cc]
    __shared__ float sc[64][16];   // scale[s][r]
    __shared__ float redm[16][16];
    __shared__ float mgl[16], lgl[16];
    int t = threadIdx.x;
    int c0 = blockIdx.x * 64; int h = blockIdx.y; int z = blockIdx.z;
    #pragma unroll
    for (int i = 0; i < 4; i++) {
        int f = t + i * 256; int cc = f >> 4, e4 = f & 15;
        *(float4*)&Wv[cc][e4 * 4] =
            *(const float4*)&Wkv[(size_t)(c0 + cc) * 1024 + 512 + h * 64 + e4 * 4];
    }
    // scale factors over ALL 64 s (global m, l)
    int r = t & 15, sg = t >> 4;   // 16 s-groups x 4 s
    int b = r >> 2, m = r & 3;
    float pm = -1e30f;
    #pragma unroll
    for (int k = 0; k < 4; k++) {
        int s = sg * 4 + k;
        pm = fmaxf(pm, mloc[((size_t)(s * B_) + b) * HM_ + h * M_ + m]);
    }
    redm[sg][r] = pm;
    __syncthreads();
    if (t < 16) {
        float mgv = redm[0][t];
        #pragma unroll
        for (int k = 1; k < 16; k++) mgv = fmaxf(mgv, redm[k][t]);
        mgl[t] = mgv;
    }
    __syncthreads();
    float mgv = mgl[r];
    float pl = 0.f;
    #pragma unroll
    for (int k = 0; k < 4; k++) {
        int s = sg * 4 + k;
        float w = __expf(mloc[((size_t)(s * B_) + b) * HM_ + h * M_ + m] - mgv);
        sc[s][r] = w;
        pl += w * lloc[((size_t)(s * B_) + b) * HM_ + h * M_ + m];
    }
    redm[sg][r] = pl;
    __syncthreads();
    if (t < 16) {
        float l = redm[0][t];
        #pragma unroll
        for (int k = 1; k < 16; k++) l += redm[k][t];
        lgl[t] = 1.0f / l;
    }
    __syncthreads();
    float inv = lgl[r];
    #pragma unroll
    for (int k = 0; k < 4; k++) sc[sg * 4 + k][r] *= inv;
    __syncthreads();
    // axh = sum over this block's 16 s of scale * pax
    {
        int rr = t >> 4, c4 = t & 15;
        int bb = rr >> 2, mm = rr & 3;
        float4 a = make_float4(0.f, 0.f, 0.f, 0.f);
        #pragma unroll 8
        for (int k = 0; k < 16; k++) {
            int s = z * 16 + k;
            float w = sc[s][rr];
            float4 v = *(const float4*)&pax[(((size_t)(s * B_) + bb) * HM_ + h * M_ + mm) * 512 + c0 + c4 * 4];
            a.x += w * v.x; a.y += w * v.y; a.z += w * v.z; a.w += w * v.w;
        }
        *(float4*)&axh[rr][c4 * 4] = a;
    }
    __syncthreads();
    int e = t & 63, rg = t >> 6;
    float acc[4] = {0, 0, 0, 0};
    #pragma unroll 16
    for (int cc = 0; cc < 64; cc++) {
        float w = Wv[cc][e];
        #pragma unroll
        for (int i = 0; i < 4; i++) acc[i] += axh[rg * 4 + i][cc] * w;
    }
    int slice = z * 8 + blockIdx.x;
    #pragma unroll
    for (int i = 0; i < 4; i++) {
        int rr = rg * 4 + i;
        ov_part[((size_t)slice * 16 + rr) * 512 + h * 64 + e] = acc[i];
    }
}

// out[r][j] = bo[j] + sum_i ov[r][i] * Wo[i][j];  ov = sum over 32 slices. atomic over i-split.
__global__ __launch_bounds__(256) void k5b_out(const float* __restrict__ Wo, const float* __restrict__ bo,
                                               const float* __restrict__ ov_part, float* __restrict__ out) {
    __shared__ float W[64][68];
    __shared__ float ovr[16][68];
    int t = threadIdx.x;
    int i0 = blockIdx.x * 64; int j0 = blockIdx.y * 64;
    #pragma unroll
    for (int i = 0; i < 4; i++) {
        int f = t + i * 256; int ii = f >> 4, j4 = f & 15;
        *(float4*)&W[ii][j4 * 4] = *(const float4*)&Wo[(size_t)(i0 + ii) * 512 + j0 + j4 * 4];
    }
    {
        int r = t >> 4, c4 = t & 15;
        float4 a = make_float4(0.f, 0.f, 0.f, 0.f);
        #pragma unroll 8
        for (int cs = 0; cs < 32; cs++) {
            float4 v = *(const float4*)&ov_part[((size_t)cs * 16 + r) * 512 + i0 + c4 * 4];
            a.x += v.x; a.y += v.y; a.z += v.z; a.w += v.w;
        }
        *(float4*)&ovr[r][c4 * 4] = a;
    }
    __syncthreads();
    int j = t & 63, rg = t >> 6;
    float binit = (blockIdx.x == 0) ? bo[j0 + j] : 0.f;
    float acc[4] = {binit, binit, binit, binit};
    #pragma unroll 16
    for (int ii = 0; ii < 64; ii++) {
        float w = W[ii][j];
        #pragma unroll
        for (int i = 0; i < 4; i++) acc[i] += ovr[rg * 4 + i][ii] * w;
    }
    #pragma unroll
    for (int i = 0; i < 4; i++) {
        int r = rg * 4 + i;
        atomicAdd(&out[r * 512 + j0 + j], acc[i]);
    }
}

extern "C" void kernel_launch(void* const* d_in, const int* in_sizes, int n_in,
                              void* d_out, int out_size, void* d_ws, size_t ws_size,
                              hipStream_t stream) {
    (void)in_sizes; (void)n_in; (void)out_size; (void)ws_size;
    const float* x    = (const float*)d_in[0];
    const float* bias = (const float*)d_in[1];
    const float* Wq   = (const float*)d_in[2];
    const float* Wkv  = (const float*)d_in[3];
    const float* Wo   = (const float*)d_in[4];
    const float* bo   = (const float*)d_in[5];
    float* out = (float*)d_out;
    float* ws  = (float*)d_ws;

    float* qk_ws   = ws + QK_OFF;
    float* pax     = ws + PAX_OFF;
    float* mloc    = ws + MLOC_OFF;
    float* lloc    = ws + LLOC_OFF;
    float* ov_part = ws + OVP_OFF;

    k1_qk<<<dim3(8, 8), 256, 0, stream>>>(x, Wq, Wkv, qk_ws, out);
    k234_flash<<<dim3(S_, B_), 256, 0, stream>>>(x, qk_ws, bias, pax, mloc, lloc);
    k5a_ov<<<dim3(8, 8, 4), 256, 0, stream>>>(Wkv, pax, mloc, lloc, ov_part);
    k5b_out<<<dim3(8, 8), 256, 0, stream>>>(Wo, bo, ov_part, out);
}